// Round 1
// baseline (426.721 us; speedup 1.0000x reference)
//
#include <hip/hip_runtime.h>
#include <hip/hip_bf16.h>
#include <stdint.h>

#define D 1024
#define TEMP_INV (1.0f / 0.92f)
#define LOG2E 1.44269504f
#define EPS 1e-6f

typedef float f32x4_t __attribute__((ext_vector_type(4)));
typedef int   i32x4_t __attribute__((ext_vector_type(4)));
typedef int   i32x8_t __attribute__((ext_vector_type(8)));

typedef __attribute__((address_space(3))) void as3_void;
typedef const __attribute__((address_space(1))) void as1_void_c;

__device__ __forceinline__ void async_copy16(const uint8_t* g, uint8_t* l) {
    __builtin_amdgcn_global_load_lds((as1_void_c*)g, (as3_void*)l, 16, 0, 0);
}

// compiler memory fence + raw workgroup barrier (NO implicit vmcnt drain —
// that drain is exactly the stall we're removing; waits are explicit below)
#define MEMFENCE() asm volatile("" ::: "memory")
#define BARRIER()  do { MEMFENCE(); __builtin_amdgcn_s_barrier(); MEMFENCE(); } while (0)

// ---------------------------------------------------------------------------
// Kernel 1: unchanged (verified). fp8 convert + norms + s1 + rowsum zero.
// ---------------------------------------------------------------------------
__global__ __launch_bounds__(256) void prep_kernel(
    const float* __restrict__ q, const float* __restrict__ p,
    const float* __restrict__ neg,
    uint8_t* __restrict__ Qb, uint8_t* __restrict__ Nb,
    float* __restrict__ iq, float* __restrict__ inx,
    float* __restrict__ s1, float* __restrict__ rowsum, int B)
{
    const int lane = threadIdx.x & 63;
    const int wid  = threadIdx.x >> 6;
    const int row  = blockIdx.x * 4 + wid;

    if (row < B) {
        const float4* qr = (const float4*)(q + (size_t)row * D);
        const float4* pr = (const float4*)(p + (size_t)row * D);
        int* qo = (int*)(Qb + (size_t)row * D);
        float qq = 0.f, pp = 0.f, qp = 0.f;
        #pragma unroll
        for (int i = 0; i < 4; ++i) {
            const int idx = i * 64 + lane;
            const float4 qv = qr[idx];
            const float4 pv = pr[idx];
            int pk = __builtin_amdgcn_cvt_pk_fp8_f32(qv.x, qv.y, 0, false);
            pk     = __builtin_amdgcn_cvt_pk_fp8_f32(qv.z, qv.w, pk, true);
            qo[idx] = pk;
            qq += qv.x*qv.x + qv.y*qv.y + qv.z*qv.z + qv.w*qv.w;
            pp += pv.x*pv.x + pv.y*pv.y + pv.z*pv.z + pv.w*pv.w;
            qp += qv.x*pv.x + qv.y*pv.y + qv.z*pv.z + qv.w*pv.w;
        }
        #pragma unroll
        for (int off = 32; off > 0; off >>= 1) {
            qq += __shfl_down(qq, off, 64);
            pp += __shfl_down(pp, off, 64);
            qp += __shfl_down(qp, off, 64);
        }
        if (lane == 0) {
            float qnv = sqrtf(qq);
            iq[row] = (TEMP_INV * LOG2E) / fmaxf(qnv, 1e-20f);
            float den = fmaxf(qnv * sqrtf(pp), EPS);
            s1[row] = expf((qp / den) * TEMP_INV);   // exact reference path
            rowsum[row] = 0.0f;
        }
    } else {
        const int r2 = row - B;
        const float4* nr = (const float4*)(neg + (size_t)r2 * D);
        int* no = (int*)(Nb + (size_t)r2 * D);
        float ss = 0.f;
        #pragma unroll
        for (int i = 0; i < 4; ++i) {
            const int idx = i * 64 + lane;
            const float4 nv = nr[idx];
            int pk = __builtin_amdgcn_cvt_pk_fp8_f32(nv.x, nv.y, 0, false);
            pk     = __builtin_amdgcn_cvt_pk_fp8_f32(nv.z, nv.w, pk, true);
            no[idx] = pk;
            ss += nv.x*nv.x + nv.y*nv.y + nv.z*nv.z + nv.w*nv.w;
        }
        #pragma unroll
        for (int off = 32; off > 0; off >>= 1) ss += __shfl_down(ss, off, 64);
        if (lane == 0) inx[r2] = 1.0f / fmaxf(sqrtf(ss), 1e-20f);
    }
}

// ---------------------------------------------------------------------------
// Kernel 2 (rewritten): 256x256 tile, 8 waves (2M x 4N), BK=128 fp8 (one
// mfma_scale 16x16x128 K-step), double-buffered 128 KiB LDS, phase-split
// K-iter with counted vmcnt (never drains to 0 in the main loop) + setprio
// around MFMA clusters. Swizzle algebra (pi-chunk permutation) is byte-for-
// byte the verified one: stored slot for (row, chunk c) = pi(c) ^ (row&7),
// pi(c) = (c>>1)|((c&1)<<2); reads rely on row&7 == lc&7 (still true: row
// bases are multiples of 16). Measured 0 bank conflicts on this layout.
//
// Pipeline (8 K-iters): stage(k+2) issued at end of iter k into the buffer
// just fully read; trailing s_waitcnt vmcnt(8) only waits for the loads
// issued one full iteration (~2200 cy of MFMA) earlier.
// ---------------------------------------------------------------------------
__global__ __launch_bounds__(512, 2) void gemm_exp_rowsum(
    const uint8_t* __restrict__ Qb, const uint8_t* __restrict__ Nb,
    const float* __restrict__ iq, const float* __restrict__ inx,
    float* __restrict__ rowsum)
{
    __shared__ __align__(16) uint8_t As[2][256 * 128];   // 2 x 32 KB
    __shared__ __align__(16) uint8_t Bs[2][256 * 128];   // 2 x 32 KB

    const int tid = threadIdx.x;          // 0..511
    const int i0 = blockIdx.y * 256;      // Q rows
    const int j0 = blockIdx.x * 256;      // Neg rows

    const int lane = tid & 63;
    const int wid  = tid >> 6;            // 0..7
    const int wm   = wid & 1;             // wave row (2x4 wave grid)
    const int wn   = wid >> 1;            // wave col 0..3
    const int quad = lane >> 4;
    const int lc   = lane & 15;

    // --- staging thread map: 512 thr x 16B = one 64-row round; 4 rounds/tile
    const int r_in = tid >> 3;            // 0..63
    const int slot = tid & 7;
    const int v    = slot ^ (r_in & 7);
    const int csw  = ((v & 3) << 1) | (v >> 2);    // pi^-1(v)
    const uint8_t* gA0 = Qb + (size_t)(i0 + r_in) * D + csw * 16;
    const uint8_t* gB0 = Nb + (size_t)(j0 + r_in) * D + csw * 16;

    auto stage = [&](int buf, int ktarg) {     // 8 global_load_lds / thread
        const uint8_t* ga = gA0 + ktarg * 128;
        const uint8_t* gb = gB0 + ktarg * 128;
        #pragma unroll
        for (int c = 0; c < 4; ++c) {
            async_copy16(ga + (size_t)c * (64 * D), &As[buf][tid * 16 + c * 8192]);
            async_copy16(gb + (size_t)c * (64 * D), &Bs[buf][tid * 16 + c * 8192]);
        }
    };

    // --- LDS read-side swizzle (verified): slot of chunk 2q / 2q+1
    const int slo = (quad ^ (lc & 7)) * 16;
    const int shi = slo ^ 64;

    f32x4_t acc[8][4];
    #pragma unroll
    for (int mi = 0; mi < 8; ++mi)
        #pragma unroll
        for (int ni = 0; ni < 4; ++ni)
            acc[mi][ni] = (f32x4_t){0.f, 0.f, 0.f, 0.f};

    union Frag { i32x8_t v8; i32x4_t v4[2]; };

    // --- prologue: 2 tiles in flight, wait only for the first
    stage(0, 0);
    stage(1, 1);
    asm volatile("s_waitcnt vmcnt(8)" ::: "memory");   // tile 0 landed
    BARRIER();

    #pragma unroll
    for (int kt = 0; kt < 8; ++kt) {
        const int cb = kt & 1;
        const uint8_t* Ab = &As[cb][(wm * 128 + lc) * 128];
        const uint8_t* Bb = &Bs[cb][(wn * 64  + lc) * 128];

        // B fragments for the whole iter (held in regs across phases)
        Frag bfr[4];
        #pragma unroll
        for (int ni = 0; ni < 4; ++ni) {
            bfr[ni].v4[0] = *(const i32x4_t*)(Bb + ni * 2048 + slo);
            bfr[ni].v4[1] = *(const i32x4_t*)(Bb + ni * 2048 + shi);
        }

        // 4 phases x {read A-pair; barrier; lgkm(0); prio1; 8 MFMA; prio0; barrier}
        #pragma unroll
        for (int ph = 0; ph < 4; ++ph) {
            Frag a0, a1;
            a0.v4[0] = *(const i32x4_t*)(Ab + (2 * ph + 0) * 2048 + slo);
            a0.v4[1] = *(const i32x4_t*)(Ab + (2 * ph + 0) * 2048 + shi);
            a1.v4[0] = *(const i32x4_t*)(Ab + (2 * ph + 1) * 2048 + slo);
            a1.v4[1] = *(const i32x4_t*)(Ab + (2 * ph + 1) * 2048 + shi);
            BARRIER();
            asm volatile("s_waitcnt lgkmcnt(0)" ::: "memory");
            __builtin_amdgcn_sched_barrier(0);
            __builtin_amdgcn_s_setprio(1);
            #pragma unroll
            for (int ni = 0; ni < 4; ++ni) {
                acc[2 * ph + 0][ni] = __builtin_amdgcn_mfma_scale_f32_16x16x128_f8f6f4(
                    a0.v8, bfr[ni].v8, acc[2 * ph + 0][ni],
                    0 /*A=fp8*/, 0 /*B=fp8*/, 0, 127, 0, 127);
                acc[2 * ph + 1][ni] = __builtin_amdgcn_mfma_scale_f32_16x16x128_f8f6f4(
                    a1.v8, bfr[ni].v8, acc[2 * ph + 1][ni],
                    0, 0, 0, 127, 0, 127);
            }
            __builtin_amdgcn_s_setprio(0);
            BARRIER();
        }

        // end of iter: all waves are past their LDS reads of buf[cb]
        // (per-wave lgkm(0) + the phase-3 trailing barrier) -> safe to restage.
        if (kt < 6) {
            stage(cb, kt + 2);                              // 8 new loads
            asm volatile("s_waitcnt vmcnt(8)" ::: "memory"); // wait tile kt+1 only
        } else {
            asm volatile("s_waitcnt vmcnt(0)" ::: "memory"); // drain for last tile
        }
        BARRIER();
    }

    // --- epilogue: e = exp2(dot * iq_i * in_j); 16-lane row-reduce; atomic.
    // C/D layout (16x16): col = lane&15, row = quad*4 + reg (verified).
    float inl[4];
    #pragma unroll
    for (int ni = 0; ni < 4; ++ni)
        inl[ni] = inx[j0 + wn * 64 + ni * 16 + lc];

    #pragma unroll
    for (int mi = 0; mi < 8; ++mi) {
        const int rbase = i0 + wm * 128 + mi * 16 + quad * 4;
        const float4 qv = *(const float4*)&iq[rbase];   // iq includes T^-1*log2e
        float qa[4] = {qv.x, qv.y, qv.z, qv.w};
        float rs[4] = {0.f, 0.f, 0.f, 0.f};
        #pragma unroll
        for (int ni = 0; ni < 4; ++ni) {
            #pragma unroll
            for (int r = 0; r < 4; ++r)
                rs[r] += __builtin_amdgcn_exp2f(acc[mi][ni][r] * qa[r] * inl[ni]);
        }
        #pragma unroll
        for (int m = 1; m < 16; m <<= 1) {
            #pragma unroll
            for (int r = 0; r < 4; ++r) rs[r] += __shfl_xor(rs[r], m, 64);
        }
        if (lc == 0) {
            #pragma unroll
            for (int r = 0; r < 4; ++r) atomicAdd(&rowsum[rbase + r], rs[r]);
        }
    }
}

// ---------------------------------------------------------------------------
// Kernel 3: unchanged (verified). loss = mean_b( log(s1+s2) - log(s1) ).
// ---------------------------------------------------------------------------
__global__ __launch_bounds__(256) void finalize_kernel(
    const float* __restrict__ s1, const float* __restrict__ rowsum,
    float* __restrict__ out, int B, float invN)
{
    __shared__ float red[4];
    const float4* s4 = (const float4*)s1;
    const float4* r4 = (const float4*)rowsum;
    float acc = 0.f;
    for (int i = threadIdx.x; i < B / 4; i += 256) {
        float4 a = s4[i];
        float4 s = r4[i];
        acc += __logf(a.x + s.x * invN) - __logf(a.x);
        acc += __logf(a.y + s.y * invN) - __logf(a.y);
        acc += __logf(a.z + s.z * invN) - __logf(a.z);
        acc += __logf(a.w + s.w * invN) - __logf(a.w);
    }
    #pragma unroll
    for (int off = 32; off > 0; off >>= 1) acc += __shfl_down(acc, off, 64);
    if ((threadIdx.x & 63) == 0) red[threadIdx.x >> 6] = acc;
    __syncthreads();
    if (threadIdx.x == 0)
        out[0] = (red[0] + red[1] + red[2] + red[3]) / (float)B;
}

extern "C" void kernel_launch(void* const* d_in, const int* in_sizes, int n_in,
                              void* d_out, int out_size, void* d_ws, size_t ws_size,
                              hipStream_t stream) {
    const float* q   = (const float*)d_in[0];
    const float* p   = (const float*)d_in[1];
    const float* neg = (const float*)d_in[2];
    const int B = in_sizes[0] / D;
    const int N = in_sizes[2] / D;

    char* ws = (char*)d_ws;
    uint8_t* Qb     = (uint8_t*)ws;
    uint8_t* Nb     = (uint8_t*)(ws + (size_t)B * D);
    float*   iq     = (float*)(ws + (size_t)(B + N) * D);
    float*   inx    = iq + B;
    float*   s1     = inx + N;
    float*   rowsum = s1 + B;

    prep_kernel<<<(B + N) / 4, 256, 0, stream>>>(q, p, neg, Qb, Nb, iq, inx, s1, rowsum, B);
    gemm_exp_rowsum<<<dim3(N / 256, B / 256), 512, 0, stream>>>(Qb, Nb, iq, inx, rowsum);
    finalize_kernel<<<1, 256, 0, stream>>>(s1, rowsum, (float*)d_out, B, 1.0f / (float)N);
}

// Round 2
// 426.294 us; speedup vs baseline: 1.0010x; 1.0010x over previous
//
#include <hip/hip_runtime.h>
#include <hip/hip_bf16.h>
#include <stdint.h>

#define D 1024
#define TEMP_INV (1.0f / 0.92f)
#define LOG2E 1.44269504f
#define EPS 1e-6f

typedef float f32x4_t __attribute__((ext_vector_type(4)));
typedef int   i32x4_t __attribute__((ext_vector_type(4)));
typedef int   i32x8_t __attribute__((ext_vector_type(8)));

typedef __attribute__((address_space(3))) void as3_void;
typedef const __attribute__((address_space(1))) void as1_void_c;

__device__ __forceinline__ void async_copy16(const uint8_t* g, uint8_t* l) {
    __builtin_amdgcn_global_load_lds((as1_void_c*)g, (as3_void*)l, 16, 0, 0);
}

// compiler memory fence + raw workgroup barrier (NO implicit vmcnt drain)
#define MEMFENCE() asm volatile("" ::: "memory")
#define BARRIER()  do { MEMFENCE(); __builtin_amdgcn_s_barrier(); MEMFENCE(); } while (0)

// ---------------------------------------------------------------------------
// Kernel 1: unchanged (verified). fp8 convert + norms + s1 + rowsum zero.
// ---------------------------------------------------------------------------
__global__ __launch_bounds__(256) void prep_kernel(
    const float* __restrict__ q, const float* __restrict__ p,
    const float* __restrict__ neg,
    uint8_t* __restrict__ Qb, uint8_t* __restrict__ Nb,
    float* __restrict__ iq, float* __restrict__ inx,
    float* __restrict__ s1, float* __restrict__ rowsum, int B)
{
    const int lane = threadIdx.x & 63;
    const int wid  = threadIdx.x >> 6;
    const int row  = blockIdx.x * 4 + wid;

    if (row < B) {
        const float4* qr = (const float4*)(q + (size_t)row * D);
        const float4* pr = (const float4*)(p + (size_t)row * D);
        int* qo = (int*)(Qb + (size_t)row * D);
        float qq = 0.f, pp = 0.f, qp = 0.f;
        #pragma unroll
        for (int i = 0; i < 4; ++i) {
            const int idx = i * 64 + lane;
            const float4 qv = qr[idx];
            const float4 pv = pr[idx];
            int pk = __builtin_amdgcn_cvt_pk_fp8_f32(qv.x, qv.y, 0, false);
            pk     = __builtin_amdgcn_cvt_pk_fp8_f32(qv.z, qv.w, pk, true);
            qo[idx] = pk;
            qq += qv.x*qv.x + qv.y*qv.y + qv.z*qv.z + qv.w*qv.w;
            pp += pv.x*pv.x + pv.y*pv.y + pv.z*pv.z + pv.w*pv.w;
            qp += qv.x*pv.x + qv.y*pv.y + qv.z*pv.z + qv.w*pv.w;
        }
        #pragma unroll
        for (int off = 32; off > 0; off >>= 1) {
            qq += __shfl_down(qq, off, 64);
            pp += __shfl_down(pp, off, 64);
            qp += __shfl_down(qp, off, 64);
        }
        if (lane == 0) {
            float qnv = sqrtf(qq);
            iq[row] = (TEMP_INV * LOG2E) / fmaxf(qnv, 1e-20f);
            float den = fmaxf(qnv * sqrtf(pp), EPS);
            s1[row] = expf((qp / den) * TEMP_INV);   // exact reference path
            rowsum[row] = 0.0f;
        }
    } else {
        const int r2 = row - B;
        const float4* nr = (const float4*)(neg + (size_t)r2 * D);
        int* no = (int*)(Nb + (size_t)r2 * D);
        float ss = 0.f;
        #pragma unroll
        for (int i = 0; i < 4; ++i) {
            const int idx = i * 64 + lane;
            const float4 nv = nr[idx];
            int pk = __builtin_amdgcn_cvt_pk_fp8_f32(nv.x, nv.y, 0, false);
            pk     = __builtin_amdgcn_cvt_pk_fp8_f32(nv.z, nv.w, pk, true);
            no[idx] = pk;
            ss += nv.x*nv.x + nv.y*nv.y + nv.z*nv.z + nv.w*nv.w;
        }
        #pragma unroll
        for (int off = 32; off > 0; off >>= 1) ss += __shfl_down(ss, off, 64);
        if (lane == 0) inx[r2] = 1.0f / fmaxf(sqrtf(ss), 1e-20f);
    }
}

// ---------------------------------------------------------------------------
// Kernel 2: 256x256 tile, 8 waves (2M x 4N), BK=128 fp8, double-buffered
// 128 KiB LDS, 4-phase K-iter with counted vmcnt + setprio. Identical to the
// round-1 source EXCEPT __launch_bounds__: (512,2) was interpreted as
// 2 blocks/CU -> 128-VGPR cap -> 1.1 GB of scratch spill traffic (measured:
// WRITE_SIZE 675 MB). Plain (512) lets the allocator use the full 256-VGPR
// budget (2 waves/SIMD schedulability limit for an 8-wave block) -> no spill.
// ---------------------------------------------------------------------------
__global__ __launch_bounds__(512) void gemm_exp_rowsum(
    const uint8_t* __restrict__ Qb, const uint8_t* __restrict__ Nb,
    const float* __restrict__ iq, const float* __restrict__ inx,
    float* __restrict__ rowsum)
{
    __shared__ __align__(16) uint8_t As[2][256 * 128];   // 2 x 32 KB
    __shared__ __align__(16) uint8_t Bs[2][256 * 128];   // 2 x 32 KB

    const int tid = threadIdx.x;          // 0..511
    const int i0 = blockIdx.y * 256;      // Q rows
    const int j0 = blockIdx.x * 256;      // Neg rows

    const int lane = tid & 63;
    const int wid  = tid >> 6;            // 0..7
    const int wm   = wid & 1;             // wave row (2x4 wave grid)
    const int wn   = wid >> 1;            // wave col 0..3
    const int quad = lane >> 4;
    const int lc   = lane & 15;

    // --- staging thread map: 512 thr x 16B = one 64-row round; 4 rounds/tile
    const int r_in = tid >> 3;            // 0..63
    const int slot = tid & 7;
    const int v    = slot ^ (r_in & 7);
    const int csw  = ((v & 3) << 1) | (v >> 2);    // pi^-1(v)
    const uint8_t* gA0 = Qb + (size_t)(i0 + r_in) * D + csw * 16;
    const uint8_t* gB0 = Nb + (size_t)(j0 + r_in) * D + csw * 16;

    auto stage = [&](int buf, int ktarg) {     // 8 global_load_lds / thread
        const uint8_t* ga = gA0 + ktarg * 128;
        const uint8_t* gb = gB0 + ktarg * 128;
        #pragma unroll
        for (int c = 0; c < 4; ++c) {
            async_copy16(ga + (size_t)c * (64 * D), &As[buf][tid * 16 + c * 8192]);
            async_copy16(gb + (size_t)c * (64 * D), &Bs[buf][tid * 16 + c * 8192]);
        }
    };

    // --- LDS read-side swizzle (verified): slot of chunk 2q / 2q+1
    const int slo = (quad ^ (lc & 7)) * 16;
    const int shi = slo ^ 64;

    f32x4_t acc[8][4];
    #pragma unroll
    for (int mi = 0; mi < 8; ++mi)
        #pragma unroll
        for (int ni = 0; ni < 4; ++ni)
            acc[mi][ni] = (f32x4_t){0.f, 0.f, 0.f, 0.f};

    union Frag { i32x8_t v8; i32x4_t v4[2]; };

    // --- prologue: 2 tiles in flight, wait only for the first
    stage(0, 0);
    stage(1, 1);
    asm volatile("s_waitcnt vmcnt(8)" ::: "memory");   // tile 0 landed
    BARRIER();

    #pragma unroll
    for (int kt = 0; kt < 8; ++kt) {
        const int cb = kt & 1;
        const uint8_t* Ab = &As[cb][(wm * 128 + lc) * 128];
        const uint8_t* Bb = &Bs[cb][(wn * 64  + lc) * 128];

        // B fragments for the whole iter (held in regs across phases)
        Frag bfr[4];
        #pragma unroll
        for (int ni = 0; ni < 4; ++ni) {
            bfr[ni].v4[0] = *(const i32x4_t*)(Bb + ni * 2048 + slo);
            bfr[ni].v4[1] = *(const i32x4_t*)(Bb + ni * 2048 + shi);
        }

        // 4 phases x {read A-pair; barrier; lgkm(0); prio1; 8 MFMA; prio0; barrier}
        #pragma unroll
        for (int ph = 0; ph < 4; ++ph) {
            Frag a0, a1;
            a0.v4[0] = *(const i32x4_t*)(Ab + (2 * ph + 0) * 2048 + slo);
            a0.v4[1] = *(const i32x4_t*)(Ab + (2 * ph + 0) * 2048 + shi);
            a1.v4[0] = *(const i32x4_t*)(Ab + (2 * ph + 1) * 2048 + slo);
            a1.v4[1] = *(const i32x4_t*)(Ab + (2 * ph + 1) * 2048 + shi);
            BARRIER();
            asm volatile("s_waitcnt lgkmcnt(0)" ::: "memory");
            __builtin_amdgcn_sched_barrier(0);
            __builtin_amdgcn_s_setprio(1);
            #pragma unroll
            for (int ni = 0; ni < 4; ++ni) {
                acc[2 * ph + 0][ni] = __builtin_amdgcn_mfma_scale_f32_16x16x128_f8f6f4(
                    a0.v8, bfr[ni].v8, acc[2 * ph + 0][ni],
                    0 /*A=fp8*/, 0 /*B=fp8*/, 0, 127, 0, 127);
                acc[2 * ph + 1][ni] = __builtin_amdgcn_mfma_scale_f32_16x16x128_f8f6f4(
                    a1.v8, bfr[ni].v8, acc[2 * ph + 1][ni],
                    0, 0, 0, 127, 0, 127);
            }
            __builtin_amdgcn_s_setprio(0);
            BARRIER();
        }

        // end of iter: all waves are past their LDS reads of buf[cb] -> restage.
        if (kt < 6) {
            stage(cb, kt + 2);                              // 8 new loads
            asm volatile("s_waitcnt vmcnt(8)" ::: "memory"); // wait tile kt+1 only
        } else {
            asm volatile("s_waitcnt vmcnt(0)" ::: "memory"); // drain for last tile
        }
        BARRIER();
    }

    // --- epilogue: e = exp2(dot * iq_i * in_j); 16-lane row-reduce; atomic.
    // C/D layout (16x16): col = lane&15, row = quad*4 + reg (verified).
    float inl[4];
    #pragma unroll
    for (int ni = 0; ni < 4; ++ni)
        inl[ni] = inx[j0 + wn * 64 + ni * 16 + lc];

    #pragma unroll
    for (int mi = 0; mi < 8; ++mi) {
        const int rbase = i0 + wm * 128 + mi * 16 + quad * 4;
        const float4 qv = *(const float4*)&iq[rbase];   // iq includes T^-1*log2e
        float qa[4] = {qv.x, qv.y, qv.z, qv.w};
        float rs[4] = {0.f, 0.f, 0.f, 0.f};
        #pragma unroll
        for (int ni = 0; ni < 4; ++ni) {
            #pragma unroll
            for (int r = 0; r < 4; ++r)
                rs[r] += __builtin_amdgcn_exp2f(acc[mi][ni][r] * qa[r] * inl[ni]);
        }
        #pragma unroll
        for (int m = 1; m < 16; m <<= 1) {
            #pragma unroll
            for (int r = 0; r < 4; ++r) rs[r] += __shfl_xor(rs[r], m, 64);
        }
        if (lc == 0) {
            #pragma unroll
            for (int r = 0; r < 4; ++r) atomicAdd(&rowsum[rbase + r], rs[r]);
        }
    }
}

// ---------------------------------------------------------------------------
// Kernel 3: unchanged (verified). loss = mean_b( log(s1+s2) - log(s1) ).
// ---------------------------------------------------------------------------
__global__ __launch_bounds__(256) void finalize_kernel(
    const float* __restrict__ s1, const float* __restrict__ rowsum,
    float* __restrict__ out, int B, float invN)
{
    __shared__ float red[4];
    const float4* s4 = (const float4*)s1;
    const float4* r4 = (const float4*)rowsum;
    float acc = 0.f;
    for (int i = threadIdx.x; i < B / 4; i += 256) {
        float4 a = s4[i];
        float4 s = r4[i];
        acc += __logf(a.x + s.x * invN) - __logf(a.x);
        acc += __logf(a.y + s.y * invN) - __logf(a.y);
        acc += __logf(a.z + s.z * invN) - __logf(a.z);
        acc += __logf(a.w + s.w * invN) - __logf(a.w);
    }
    #pragma unroll
    for (int off = 32; off > 0; off >>= 1) acc += __shfl_down(acc, off, 64);
    if ((threadIdx.x & 63) == 0) red[threadIdx.x >> 6] = acc;
    __syncthreads();
    if (threadIdx.x == 0)
        out[0] = (red[0] + red[1] + red[2] + red[3]) / (float)B;
}

extern "C" void kernel_launch(void* const* d_in, const int* in_sizes, int n_in,
                              void* d_out, int out_size, void* d_ws, size_t ws_size,
                              hipStream_t stream) {
    const float* q   = (const float*)d_in[0];
    const float* p   = (const float*)d_in[1];
    const float* neg = (const float*)d_in[2];
    const int B = in_sizes[0] / D;
    const int N = in_sizes[2] / D;

    char* ws = (char*)d_ws;
    uint8_t* Qb     = (uint8_t*)ws;
    uint8_t* Nb     = (uint8_t*)(ws + (size_t)B * D);
    float*   iq     = (float*)(ws + (size_t)(B + N) * D);
    float*   inx    = iq + B;
    float*   s1     = inx + N;
    float*   rowsum = s1 + B;

    prep_kernel<<<(B + N) / 4, 256, 0, stream>>>(q, p, neg, Qb, Nb, iq, inx, s1, rowsum, B);
    gemm_exp_rowsum<<<dim3(N / 256, B / 256), 512, 0, stream>>>(Qb, Nb, iq, inx, rowsum);
    finalize_kernel<<<1, 256, 0, stream>>>(s1, rowsum, (float*)d_out, B, 1.0f / (float)N);
}